// Round 6
// baseline (816.579 us; speedup 1.0000x reference)
//
#include <hip/hip_runtime.h>
#include <hip/hip_fp16.h>

// GraphNN_KNN: N=50000 nodes, E=800000 edges, H=64.
// msg = relu([x_i, x_j-x_i, ef] @ W + b) == relu(u[dst] + v[src] + ef*we)
// with u = x@(Wt-Wm)+b, v = x@Wm. u/v GEMMs: MFMA 16x16x32_f16, split-fp16
// (x=xh+xl, W=Wh+Wl; 3 terms) for fp32-level accuracy; u/v stored fp16.
// Edge passes: 8 nodes/wave, 8 lanes/node, 16B fp16 gathers.
// CSR build: count w/ 32B-strided counters (atomic sector-serialization probe)
// + rank capture -> scan -> XCD-class fill (write locality: all writes to an
// em_val/ec_val line come from one block class -> one XCD under the usual
// round-robin mapping; correctness independent of the mapping).

#define NN 50000
#define NE 800000
#define PER 200000      // E / 4 orders
#define HD 64
#define NKEY 250112     // 4*NN em keys + NN ec keys, padded to 977*256
#define CSTR 8          // counter stride (ints) -> 32B sector per counter

typedef _Float16 half8 __attribute__((ext_vector_type(8)));
typedef float float4v __attribute__((ext_vector_type(4)));

// ---------------- CSR build ----------------
__global__ __launch_bounds__(256) void count_kernel(
        const int* __restrict__ ei, int* __restrict__ cnt,
        uchar2* __restrict__ rank) {
    int e = blockIdx.x * 256 + threadIdx.x;
    if (e >= NE) return;
    int src = ei[e];
    int dst = ei[NE + e];
    int o = e / PER;
    int r1 = atomicAdd(&cnt[(o * NN + src) * CSTR], 1);
    int r2 = atomicAdd(&cnt[(4 * NN + dst) * CSTR], 1);
    rank[e] = make_uchar2((unsigned char)r1, (unsigned char)r2);
}

__global__ __launch_bounds__(256) void scan_blk(
        const int* __restrict__ cnt, int* __restrict__ bsum) {
    __shared__ int s[256];
    int t = threadIdx.x;
    int i = blockIdx.x * 256 + t;
    int c = (i < NKEY) ? cnt[(size_t)i * CSTR] : 0;
    s[t] = c; __syncthreads();
    for (int d = 1; d < 256; d <<= 1) {
        int v = (t >= d) ? s[t - d] : 0;
        __syncthreads(); s[t] += v; __syncthreads();
    }
    if (t == 255) bsum[blockIdx.x] = s[255];
}

__global__ __launch_bounds__(1024) void scan_top(
        const int* __restrict__ bsum, int* __restrict__ bofs, int nb) {
    __shared__ int s[1024];
    int t = threadIdx.x;
    int c = (t < nb) ? bsum[t] : 0;
    s[t] = c; __syncthreads();
    for (int d = 1; d < 1024; d <<= 1) {
        int v = (t >= d) ? s[t - d] : 0;
        __syncthreads(); s[t] += v; __syncthreads();
    }
    if (t < nb) bofs[t] = s[t] - c;  // exclusive
}

__global__ __launch_bounds__(256) void scan_fin(
        const int* __restrict__ cnt, const int* __restrict__ bofs,
        int* __restrict__ ofs) {
    __shared__ int s[256];
    int t = threadIdx.x;
    int i = blockIdx.x * 256 + t;
    int c = (i < NKEY) ? cnt[(size_t)i * CSTR] : 0;
    s[t] = c; __syncthreads();
    for (int d = 1; d < 256; d <<= 1) {
        int v = (t >= d) ? s[t - d] : 0;
        __syncthreads(); s[t] += v; __syncthreads();
    }
    if (i < NKEY) ofs[i] = bofs[blockIdx.x] + s[t] - c;  // exclusive
}

// XCD-class fill: 1024 blocks = 128 slices x 8 classes. Block (slice, cls)
// scans its 6250-edge slice, writes em entries with (src>>3)&7==cls and ec
// entries with (dst>>3)&7==cls. em value = dst<<16 | fp16(ef); ec value = src.
__global__ __launch_bounds__(256) void fill_xcd(
        const int* __restrict__ ei, const float* __restrict__ ef,
        const int* __restrict__ ofs, const uchar2* __restrict__ rank,
        unsigned* __restrict__ em_val, int* __restrict__ ec_val) {
    int cls = blockIdx.x & 7;
    int base = (blockIdx.x >> 3) * (NE / 128);
    for (int i = threadIdx.x; i < NE / 128; i += 256) {
        int e = base + i;
        int src = ei[e];
        int dst = ei[NE + e];
        uchar2 r = rank[e];
        if (((src >> 3) & 7) == cls) {
            int o = e / PER;
            int p1 = ofs[o * NN + src] + r.x;
            unsigned short eb = __half_as_ushort(__float2half_rn(ef[e]));
            em_val[p1] = ((unsigned)dst << 16) | (unsigned)eb;
        }
        if (((dst >> 3) & 7) == cls) {
            int p2 = ofs[4 * NN + dst] + r.y - NE;
            ec_val[p2] = src;
        }
    }
}

// ---------------- weight prep: split-fp16, transposed [n][k] ---------------
// mats 0-2 emWu, 3-5 emWv, 6-8 ecWu, 9-11 ecWv; lo parts at +12 mats.
__global__ __launch_bounds__(256) void prep_w(
        const float* __restrict__ em_w, const float* __restrict__ ec_w,
        _Float16* __restrict__ wh) {
    int idx = blockIdx.x * 256 + threadIdx.x;   // < 12*4096
    int mat = idx >> 12, pos = idx & 4095;
    int n = pos >> 6, k = pos & 63;
    float val;
    if (mat < 3)      { const float* B = em_w + mat * 129 * 64;     val = B[k*64+n] - B[(64+k)*64+n]; }
    else if (mat < 6) { const float* B = em_w + (mat-3) * 129 * 64; val = B[(64+k)*64+n]; }
    else if (mat < 9) { const float* B = ec_w + (mat-6) * 128 * 64; val = B[k*64+n] - B[(64+k)*64+n]; }
    else              { const float* B = ec_w + (mat-9) * 128 * 64; val = B[(64+k)*64+n]; }
    _Float16 h = (_Float16)val;
    _Float16 l = (_Float16)(val - (float)h);
    wh[(size_t)mat * 4096 + n * 64 + k] = h;
    wh[(size_t)(12 + mat) * 4096 + n * 64 + k] = l;
}

// ---------------- linear: x = relu(x @ W + b), scalar fp32 ------------------
template<int K>
__global__ __launch_bounds__(256) void lin_kernel(
        const float* __restrict__ xin,
        const float* __restrict__ W, const float* __restrict__ bias,
        float* __restrict__ xout) {
    __shared__ float xs[64][K + 1];
    int t = threadIdx.x;
    int n0 = blockIdx.x * 64;
    for (int idx = t; idx < 64 * K; idx += 256) {
        int n = idx / K, k = idx - n * K;
        int g = n0 + n;
        xs[n][k] = (g < NN) ? xin[(size_t)g * K + k] : 0.f;
    }
    __syncthreads();
    int ng = t >> 4;
    int f0 = (t & 15) * 4;
    float acc[4][4] = {};
    for (int k = 0; k < K; ++k) {
        float4 w4 = *(const float4*)&W[k * HD + f0];
        #pragma unroll
        for (int j = 0; j < 4; ++j) {
            float xv = xs[ng * 4 + j][k];
            acc[j][0] += xv * w4.x; acc[j][1] += xv * w4.y;
            acc[j][2] += xv * w4.z; acc[j][3] += xv * w4.w;
        }
    }
    float4 b4 = *(const float4*)&bias[f0];
    #pragma unroll
    for (int j = 0; j < 4; ++j) {
        int g = n0 + ng * 4 + j;
        if (g < NN) {
            float4 o;
            o.x = fmaxf(acc[j][0] + b4.x, 0.f);
            o.y = fmaxf(acc[j][1] + b4.y, 0.f);
            o.z = fmaxf(acc[j][2] + b4.z, 0.f);
            o.w = fmaxf(acc[j][3] + b4.w, 0.f);
            *(float4*)&xout[(size_t)g * HD + f0] = o;
        }
    }
}

// ---------------- u/v via MFMA, split-fp16 ---------------------------------
// u = x@Wu + b, v = x@Wv. 64 nodes/block, 4 waves, wave w -> rows w*16..
// LDS: x staged fp32 (split h/l at A-frag load), W staged fp16 pad-68,
// repack buffer aliases the x region -> 51.7KB -> 3 blocks/CU.
__global__ __launch_bounds__(256) void uv_mfma(
        const float* __restrict__ x,
        const _Float16* __restrict__ Wuh, const _Float16* __restrict__ Wul,
        const _Float16* __restrict__ Wvh, const _Float16* __restrict__ Wvl,
        const float* __restrict__ bias,
        _Float16* __restrict__ u, _Float16* __restrict__ v) {
    __shared__ __align__(16) char smem[64 * 66 * 4 + 4 * 64 * 68 * 2];
    float* xs = (float*)smem;                        // 64 rows x 66 floats
    _Float16* wlds = (_Float16*)(smem + 64 * 66 * 4); // 4 mats x 64 x 68
    _Float16* rp = (_Float16*)smem;                  // alias xs (after barrier)
    int t = threadIdx.x;
    int n0 = blockIdx.x * 64;

    { // stage x fp32: thread t -> node t>>2, 16 cols at (t&3)*16
        int node = t >> 2, k0 = (t & 3) * 16;
        int g = n0 + node;
        float4 f0v, f1v, f2v, f3v;
        if (g < NN) {
            const float4* xr = (const float4*)&x[(size_t)g * HD + k0];
            f0v = xr[0]; f1v = xr[1]; f2v = xr[2]; f3v = xr[3];
        } else {
            f0v = f1v = f2v = f3v = make_float4(0.f, 0.f, 0.f, 0.f);
        }
        float* d = &xs[node * 66 + k0];
        *(float4*)&d[0] = f0v; *(float4*)&d[4] = f1v;
        *(float4*)&d[8] = f2v; *(float4*)&d[12] = f3v;
    }
    { // stage W: 4 mats, thread t -> row t>>2, 16 halves at (t&3)*16
        int row = t >> 2, c = (t & 3) * 16;
        const _Float16* srcs[4] = {Wuh, Wul, Wvh, Wvl};
        #pragma unroll
        for (int m = 0; m < 4; ++m) {
            _Float16* d = &wlds[m * 64 * 68 + row * 68 + c];
            *(half8*)&d[0] = *(const half8*)&srcs[m][row * 64 + c];
            *(half8*)&d[8] = *(const half8*)&srcs[m][row * 64 + c + 8];
        }
    }
    __syncthreads();

    int w = t >> 6, lane = t & 63;
    int quad = lane >> 4, l16 = lane & 15;
    int m0 = w * 16;
    // A-frags: read 16 fp32 from xs, split to h/l half8
    half8 ah0, ah1, al0, al1;
    {
        const float* r0 = &xs[(m0 + l16) * 66 + quad * 8];
        const float* r1 = &xs[(m0 + l16) * 66 + 32 + quad * 8];
        #pragma unroll
        for (int j = 0; j < 8; ++j) {
            float f = r0[j];
            _Float16 h = (_Float16)f;
            ah0[j] = h; al0[j] = (_Float16)(f - (float)h);
            float g2 = r1[j];
            _Float16 h2 = (_Float16)g2;
            ah1[j] = h2; al1[j] = (_Float16)(g2 - (float)h2);
        }
    }
    __syncthreads();  // xs dead; rp may now alias it

    float4v au[4], av[4];
    #pragma unroll
    for (int nt = 0; nt < 4; ++nt) {
        int n = nt * 16 + l16;
        const _Float16* bu_h = &wlds[0 * 64 * 68 + n * 68];
        const _Float16* bu_l = &wlds[1 * 64 * 68 + n * 68];
        const _Float16* bv_h = &wlds[2 * 64 * 68 + n * 68];
        const _Float16* bv_l = &wlds[3 * 64 * 68 + n * 68];
        half8 bh0 = *(const half8*)&bu_h[quad * 8];
        half8 bh1 = *(const half8*)&bu_h[32 + quad * 8];
        half8 bl0 = *(const half8*)&bu_l[quad * 8];
        half8 bl1 = *(const half8*)&bu_l[32 + quad * 8];
        float4v acc = {0.f, 0.f, 0.f, 0.f};
        acc = __builtin_amdgcn_mfma_f32_16x16x32_f16(ah0, bh0, acc, 0, 0, 0);
        acc = __builtin_amdgcn_mfma_f32_16x16x32_f16(ah1, bh1, acc, 0, 0, 0);
        acc = __builtin_amdgcn_mfma_f32_16x16x32_f16(al0, bh0, acc, 0, 0, 0);
        acc = __builtin_amdgcn_mfma_f32_16x16x32_f16(al1, bh1, acc, 0, 0, 0);
        acc = __builtin_amdgcn_mfma_f32_16x16x32_f16(ah0, bl0, acc, 0, 0, 0);
        acc = __builtin_amdgcn_mfma_f32_16x16x32_f16(ah1, bl1, acc, 0, 0, 0);
        au[nt] = acc;
        half8 ch0 = *(const half8*)&bv_h[quad * 8];
        half8 ch1 = *(const half8*)&bv_h[32 + quad * 8];
        half8 cl0 = *(const half8*)&bv_l[quad * 8];
        half8 cl1 = *(const half8*)&bv_l[32 + quad * 8];
        float4v accv = {0.f, 0.f, 0.f, 0.f};
        accv = __builtin_amdgcn_mfma_f32_16x16x32_f16(ah0, ch0, accv, 0, 0, 0);
        accv = __builtin_amdgcn_mfma_f32_16x16x32_f16(ah1, ch1, accv, 0, 0, 0);
        accv = __builtin_amdgcn_mfma_f32_16x16x32_f16(al0, ch0, accv, 0, 0, 0);
        accv = __builtin_amdgcn_mfma_f32_16x16x32_f16(al1, ch1, accv, 0, 0, 0);
        accv = __builtin_amdgcn_mfma_f32_16x16x32_f16(ah0, cl0, accv, 0, 0, 0);
        accv = __builtin_amdgcn_mfma_f32_16x16x32_f16(ah1, cl1, accv, 0, 0, 0);
        av[nt] = accv;
    }

    // repack u (+bias) through per-wave LDS (aliases xs), store 16B vectors
    _Float16* rpw = &rp[w * 16 * 72];
    #pragma unroll
    for (int nt = 0; nt < 4; ++nt) {
        float bn = bias[nt * 16 + l16];
        #pragma unroll
        for (int r = 0; r < 4; ++r)
            rpw[(quad * 4 + r) * 72 + nt * 16 + l16] = (_Float16)(au[nt][r] + bn);
    }
    int mr = lane >> 2, cr = (lane & 3) * 16;
    int gr = n0 + m0 + mr;
    if (gr < NN) {
        *(half8*)&u[(size_t)gr * HD + cr]     = *(half8*)&rpw[mr * 72 + cr];
        *(half8*)&u[(size_t)gr * HD + cr + 8] = *(half8*)&rpw[mr * 72 + cr + 8];
    }
    #pragma unroll
    for (int nt = 0; nt < 4; ++nt) {
        #pragma unroll
        for (int r = 0; r < 4; ++r)
            rpw[(quad * 4 + r) * 72 + nt * 16 + l16] = (_Float16)(av[nt][r]);
    }
    if (gr < NN) {
        *(half8*)&v[(size_t)gr * HD + cr]     = *(half8*)&rpw[mr * 72 + cr];
        *(half8*)&v[(size_t)gr * HD + cr + 8] = *(half8*)&rpw[mr * 72 + cr + 8];
    }
}

// load 8 consecutive halves (16B aligned) -> 8 floats
__device__ __forceinline__ void load_h8(const __half* p, float* o) {
    float4 r = *(const float4*)p;
    __half2 h0 = *reinterpret_cast<__half2*>(&r.x);
    __half2 h1 = *reinterpret_cast<__half2*>(&r.y);
    __half2 h2 = *reinterpret_cast<__half2*>(&r.z);
    __half2 h3 = *reinterpret_cast<__half2*>(&r.w);
    float2 f0 = __half22float2(h0), f1 = __half22float2(h1);
    float2 f2 = __half22float2(h2), f3 = __half22float2(h3);
    o[0] = f0.x; o[1] = f0.y; o[2] = f1.x; o[3] = f1.y;
    o[4] = f2.x; o[5] = f2.y; o[6] = f3.x; o[7] = f3.y;
}

// ---------------- emulsion edge pass + fold --------------------------------
// 8 nodes/wave, 8 lanes/node, 8 features/lane.
// x[n] = (x[n] + sum_e relu(u[dst]+v[n]+ef*we)) / 2   (node-local update)
__global__ __launch_bounds__(256) void em_edge(
        const unsigned* __restrict__ em_val, const int* __restrict__ ofs,
        const __half* __restrict__ u, const __half* __restrict__ v,
        const float* __restrict__ we, float* __restrict__ x, int order) {
    int t = threadIdx.x;
    int node = blockIdx.x * 32 + (t >> 3);
    if (node >= NN) return;
    int f0 = (t & 7) * 8;
    int key = order * NN + node;
    int s0 = ofs[key], s1 = ofs[key + 1];
    float vn[8], wef[8], acc[8] = {};
    load_h8(&v[(size_t)node * HD + f0], vn);
    *(float4*)&wef[0] = *(const float4*)&we[f0];
    *(float4*)&wef[4] = *(const float4*)&we[f0 + 4];
    int p = s0;
    for (; p + 2 <= s1; p += 2) {
        unsigned e0 = em_val[p], e1 = em_val[p + 1];
        float u0[8], u1[8];
        load_h8(&u[(size_t)(e0 >> 16) * HD + f0], u0);
        load_h8(&u[(size_t)(e1 >> 16) * HD + f0], u1);
        float ef0 = __half2float(__ushort_as_half((unsigned short)(e0 & 0xffff)));
        float ef1 = __half2float(__ushort_as_half((unsigned short)(e1 & 0xffff)));
        #pragma unroll
        for (int j = 0; j < 8; ++j) {
            acc[j] += fmaxf(u0[j] + vn[j] + ef0 * wef[j], 0.f)
                    + fmaxf(u1[j] + vn[j] + ef1 * wef[j], 0.f);
        }
    }
    if (p < s1) {
        unsigned e0 = em_val[p];
        float u0[8];
        load_h8(&u[(size_t)(e0 >> 16) * HD + f0], u0);
        float ef0 = __half2float(__ushort_as_half((unsigned short)(e0 & 0xffff)));
        #pragma unroll
        for (int j = 0; j < 8; ++j)
            acc[j] += fmaxf(u0[j] + vn[j] + ef0 * wef[j], 0.f);
    }
    float xr[8];
    *(float4*)&xr[0] = *(const float4*)&x[(size_t)node * HD + f0];
    *(float4*)&xr[4] = *(const float4*)&x[(size_t)node * HD + f0 + 4];
    #pragma unroll
    for (int j = 0; j < 8; ++j) xr[j] = (xr[j] + acc[j]) * 0.5f;
    *(float4*)&x[(size_t)node * HD + f0] = *(float4*)&xr[0];
    *(float4*)&x[(size_t)node * HD + f0 + 4] = *(float4*)&xr[4];
}

// ---------------- edge conv pass: x[n] = max(0, max_e (u[n]+v[src])) -------
__global__ __launch_bounds__(256) void ec_edge(
        const int* __restrict__ ec_val, const int* __restrict__ ofs,
        const __half* __restrict__ u, const __half* __restrict__ v,
        float* __restrict__ x) {
    int t = threadIdx.x;
    int node = blockIdx.x * 32 + (t >> 3);
    if (node >= NN) return;
    int f0 = (t & 7) * 8;
    int s0 = ofs[4 * NN + node] - NE, s1 = ofs[4 * NN + node + 1] - NE;
    float un[8], m[8] = {};  // init 0: empty -> 0, and relu'd msgs >= 0
    load_h8(&u[(size_t)node * HD + f0], un);
    int p = s0;
    for (; p + 2 <= s1; p += 2) {
        int i0 = ec_val[p], i1 = ec_val[p + 1];
        float v0[8], v1[8];
        load_h8(&v[(size_t)i0 * HD + f0], v0);
        load_h8(&v[(size_t)i1 * HD + f0], v1);
        #pragma unroll
        for (int j = 0; j < 8; ++j)
            m[j] = fmaxf(m[j], fmaxf(un[j] + v0[j], un[j] + v1[j]));
    }
    if (p < s1) {
        int i0 = ec_val[p];
        float v0[8];
        load_h8(&v[(size_t)i0 * HD + f0], v0);
        #pragma unroll
        for (int j = 0; j < 8; ++j) m[j] = fmaxf(m[j], un[j] + v0[j]);
    }
    *(float4*)&x[(size_t)node * HD + f0] = *(float4*)&m[0];
    *(float4*)&x[(size_t)node * HD + f0 + 4] = *(float4*)&m[4];
}

// ---------------- output projection ----------------------------------------
__global__ __launch_bounds__(256) void out_kernel(
        const float* __restrict__ x, const float* __restrict__ W,
        const float* __restrict__ bias, float* __restrict__ out) {
    int n = blockIdx.x * 256 + threadIdx.x;
    if (n >= NN) return;
    float xr[HD];
    #pragma unroll
    for (int k = 0; k < HD; k += 4) {
        float4 t4 = *(const float4*)&x[(size_t)n * HD + k];
        xr[k] = t4.x; xr[k + 1] = t4.y; xr[k + 2] = t4.z; xr[k + 3] = t4.w;
    }
    #pragma unroll
    for (int f = 0; f < 10; ++f) {
        float acc = bias[f];
        #pragma unroll
        for (int k = 0; k < HD; ++k) acc += xr[k] * W[k * 10 + f];
        out[(size_t)n * 10 + f] = acc;
    }
}

extern "C" void kernel_launch(void* const* d_in, const int* in_sizes, int n_in,
                              void* d_out, int out_size, void* d_ws, size_t ws_size,
                              hipStream_t stream) {
    const float* x_in  = (const float*)d_in[0];
    const int*   ei    = (const int*)d_in[1];
    const float* ef    = (const float*)d_in[2];
    const float* lw[3] = {(const float*)d_in[3], (const float*)d_in[5], (const float*)d_in[7]};
    const float* lb[3] = {(const float*)d_in[4], (const float*)d_in[6], (const float*)d_in[8]};
    const float* em_w  = (const float*)d_in[9];
    const float* em_b  = (const float*)d_in[10];
    const float* ec_w  = (const float*)d_in[11];
    const float* ec_b  = (const float*)d_in[12];
    const float* ow    = (const float*)d_in[13];
    const float* ob    = (const float*)d_in[14];
    float* out = (float*)d_out;

    char* wsb = (char*)d_ws;
    size_t off = 0;
    auto alloc = [&](size_t bytes) {
        void* p = wsb + off;
        off = (off + bytes + 255) & ~(size_t)255;
        return p;
    };
    float*     x      = (float*)alloc((size_t)NN * HD * 4);
    _Float16*  u      = (_Float16*)alloc((size_t)NN * HD * 2);
    _Float16*  v      = (_Float16*)alloc((size_t)NN * HD * 2);
    int*       cnt    = (int*)alloc((size_t)NKEY * CSTR * 4);
    int*       ofs    = (int*)alloc((size_t)NKEY * 4);
    int*       bsum   = (int*)alloc((size_t)1024 * 4);
    int*       bofs   = (int*)alloc((size_t)1024 * 4);
    uchar2*    rank   = (uchar2*)alloc((size_t)NE * 2);
    unsigned*  em_val = (unsigned*)alloc((size_t)NE * 4);
    int*       ec_val = (int*)alloc((size_t)NE * 4);
    _Float16*  wh     = (_Float16*)alloc((size_t)24 * 4096 * 2);
    (void)ws_size; (void)in_sizes; (void)n_in; (void)out_size;

    const int gb_nodes = (NN + 63) / 64;   // 782
    const int gb_edges = (NE + 255) / 256; // 3125
    const int gb_n8    = (NN + 31) / 32;   // 1563
    const int gb_keys  = NKEY / 256;       // 977

    // ---- CSR build + weight prep ----
    hipMemsetAsync(cnt, 0, (size_t)NKEY * CSTR * 4, stream);
    count_kernel<<<gb_edges, 256, 0, stream>>>(ei, cnt, rank);
    prep_w<<<192, 256, 0, stream>>>(em_w, ec_w, wh);
    scan_blk<<<gb_keys, 256, 0, stream>>>(cnt, bsum);
    scan_top<<<1, 1024, 0, stream>>>(bsum, bofs, gb_keys);
    scan_fin<<<gb_keys, 256, 0, stream>>>(cnt, bofs, ofs);
    fill_xcd<<<1024, 256, 0, stream>>>(ei, ef, ofs, rank, em_val, ec_val);

    // ---- network ----
    lin_kernel<10><<<gb_nodes, 256, 0, stream>>>(x_in, lw[0], lb[0], x);

    for (int i = 0; i < 3; ++i) {
        const _Float16* Wuh = wh + (size_t)i * 4096;
        const _Float16* Wvh = wh + (size_t)(3 + i) * 4096;
        const _Float16* Wul = wh + (size_t)(12 + i) * 4096;
        const _Float16* Wvl = wh + (size_t)(15 + i) * 4096;
        const float* bi = em_b + (size_t)i * HD;
        const float* we = em_w + (size_t)i * 129 * HD + 128 * HD;
        for (int o = 0; o < 4; ++o) {
            uv_mfma<<<gb_nodes, 256, 0, stream>>>(x, Wuh, Wul, Wvh, Wvl, bi, u, v);
            em_edge<<<gb_n8, 256, 0, stream>>>(em_val, ofs, (const __half*)u,
                                               (const __half*)v, we, x, o);
        }
        if (i < 2)
            lin_kernel<64><<<gb_nodes, 256, 0, stream>>>(x, lw[i + 1], lb[i + 1], x);
    }

    for (int j = 0; j < 3; ++j) {
        const _Float16* Wuh = wh + (size_t)(6 + j) * 4096;
        const _Float16* Wvh = wh + (size_t)(9 + j) * 4096;
        const _Float16* Wul = wh + (size_t)(18 + j) * 4096;
        const _Float16* Wvl = wh + (size_t)(21 + j) * 4096;
        const float* bj = ec_b + (size_t)j * HD;
        uv_mfma<<<gb_nodes, 256, 0, stream>>>(x, Wuh, Wul, Wvh, Wvl, bj, u, v);
        ec_edge<<<gb_n8, 256, 0, stream>>>(ec_val, ofs, (const __half*)u,
                                           (const __half*)v, x);
    }

    out_kernel<<<(NN + 255) / 256, 256, 0, stream>>>(x, ow, ob, out);
}

// Round 7
// 587.629 us; speedup vs baseline: 1.3896x; 1.3896x over previous
//
#include <hip/hip_runtime.h>
#include <hip/hip_fp16.h>

// GraphNN_KNN: N=50000 nodes, E=800000 edges, H=64.
// msg = relu([x_i, x_j-x_i, ef] @ W + b) == relu(u[dst] + v[src] + ef*we)
// with u = x@(Wt-Wm)+b, v = x@Wm. u/v GEMMs: MFMA 16x16x32_f16, split-fp16
// (x=xh+xl, W=Wh+Wl; 3 terms) for fp32-level accuracy; u/v stored fp16.
// Edge passes: 8 nodes/wave, 8 lanes/node, 16B fp16 gathers.
// R7: revert to the R5 (579us) config (R6 probes regressed); add (a) fused
// setup kernel (count+lin0+prep_w, independent work hidden behind the
// atomic-rate-bound count), (b) output projection fused into the last ec pass.

#define NN 50000
#define NE 800000
#define PER 200000      // E / 4 orders
#define HD 64
#define NKEY 250112     // 4*NN em keys + NN ec keys, padded to 977*256

#define NB_COUNT 3125
#define NB_LIN   782
#define NB_PREP  192

typedef _Float16 half8 __attribute__((ext_vector_type(8)));
typedef float float4v __attribute__((ext_vector_type(4)));

// ---------------- fused setup: count + lin0 + prep_w -----------------------
// blocks [0,3125): count edges (atomic rank capture)
// blocks [3125,3907): x = relu(x_in @ lin0_w + lin0_b)   (K=10)
// blocks [3907,4099): split-fp16 weight prep (12 mats + lo parts)
__global__ __launch_bounds__(256) void setup_kernel(
        const int* __restrict__ ei, int* __restrict__ cnt,
        uchar2* __restrict__ rank,
        const float* __restrict__ x_in, const float* __restrict__ lw0,
        const float* __restrict__ lb0, float* __restrict__ x,
        const float* __restrict__ em_w, const float* __restrict__ ec_w,
        _Float16* __restrict__ wh) {
    __shared__ float xs[64][11];
    int t = threadIdx.x;
    int b = blockIdx.x;
    if (b < NB_COUNT) {
        int e = b * 256 + t;
        if (e >= NE) return;
        int src = ei[e];
        int dst = ei[NE + e];
        int o = e / PER;
        int r1 = atomicAdd(&cnt[o * NN + src], 1);
        int r2 = atomicAdd(&cnt[4 * NN + dst], 1);
        rank[e] = make_uchar2((unsigned char)r1, (unsigned char)r2);
    } else if (b < NB_COUNT + NB_LIN) {
        int n0 = (b - NB_COUNT) * 64;
        for (int idx = t; idx < 64 * 10; idx += 256) {
            int n = idx / 10, k = idx - n * 10;
            int g = n0 + n;
            xs[n][k] = (g < NN) ? x_in[(size_t)g * 10 + k] : 0.f;
        }
        __syncthreads();
        int ng = t >> 4;
        int f0 = (t & 15) * 4;
        float acc[4][4] = {};
        for (int k = 0; k < 10; ++k) {
            float4 w4 = *(const float4*)&lw0[k * HD + f0];
            #pragma unroll
            for (int j = 0; j < 4; ++j) {
                float xv = xs[ng * 4 + j][k];
                acc[j][0] += xv * w4.x; acc[j][1] += xv * w4.y;
                acc[j][2] += xv * w4.z; acc[j][3] += xv * w4.w;
            }
        }
        float4 b4 = *(const float4*)&lb0[f0];
        #pragma unroll
        for (int j = 0; j < 4; ++j) {
            int g = n0 + ng * 4 + j;
            if (g < NN) {
                float4 o;
                o.x = fmaxf(acc[j][0] + b4.x, 0.f);
                o.y = fmaxf(acc[j][1] + b4.y, 0.f);
                o.z = fmaxf(acc[j][2] + b4.z, 0.f);
                o.w = fmaxf(acc[j][3] + b4.w, 0.f);
                *(float4*)&x[(size_t)g * HD + f0] = o;
            }
        }
    } else {
        int idx = (b - NB_COUNT - NB_LIN) * 256 + t;   // < 12*4096
        int mat = idx >> 12, pos = idx & 4095;
        int n = pos >> 6, k = pos & 63;
        float val;
        if (mat < 3)      { const float* B = em_w + mat * 129 * 64;     val = B[k*64+n] - B[(64+k)*64+n]; }
        else if (mat < 6) { const float* B = em_w + (mat-3) * 129 * 64; val = B[(64+k)*64+n]; }
        else if (mat < 9) { const float* B = ec_w + (mat-6) * 128 * 64; val = B[k*64+n] - B[(64+k)*64+n]; }
        else              { const float* B = ec_w + (mat-9) * 128 * 64; val = B[(64+k)*64+n]; }
        _Float16 h = (_Float16)val;
        _Float16 l = (_Float16)(val - (float)h);
        wh[(size_t)mat * 4096 + n * 64 + k] = h;
        wh[(size_t)(12 + mat) * 4096 + n * 64 + k] = l;
    }
}

// ---------------- scans ----------------
__global__ __launch_bounds__(256) void scan_blk(
        const int* __restrict__ cnt, int* __restrict__ bsum) {
    __shared__ int s[256];
    int t = threadIdx.x;
    int i = blockIdx.x * 256 + t;
    int c = (i < NKEY) ? cnt[i] : 0;
    s[t] = c; __syncthreads();
    for (int d = 1; d < 256; d <<= 1) {
        int v = (t >= d) ? s[t - d] : 0;
        __syncthreads(); s[t] += v; __syncthreads();
    }
    if (t == 255) bsum[blockIdx.x] = s[255];
}

__global__ __launch_bounds__(1024) void scan_top(
        const int* __restrict__ bsum, int* __restrict__ bofs, int nb) {
    __shared__ int s[1024];
    int t = threadIdx.x;
    int c = (t < nb) ? bsum[t] : 0;
    s[t] = c; __syncthreads();
    for (int d = 1; d < 1024; d <<= 1) {
        int v = (t >= d) ? s[t - d] : 0;
        __syncthreads(); s[t] += v; __syncthreads();
    }
    if (t < nb) bofs[t] = s[t] - c;  // exclusive
}

__global__ __launch_bounds__(256) void scan_fin(
        const int* __restrict__ cnt, const int* __restrict__ bofs,
        int* __restrict__ ofs) {
    __shared__ int s[256];
    int t = threadIdx.x;
    int i = blockIdx.x * 256 + t;
    int c = (i < NKEY) ? cnt[i] : 0;
    s[t] = c; __syncthreads();
    for (int d = 1; d < 256; d <<= 1) {
        int v = (t >= d) ? s[t - d] : 0;
        __syncthreads(); s[t] += v; __syncthreads();
    }
    if (i < NKEY) ofs[i] = bofs[blockIdx.x] + s[t] - c;  // exclusive
}

// fill (no atomics): em value = dst<<16 | fp16(ef) bits; ec value = src
__global__ __launch_bounds__(256) void fill_kernel(
        const int* __restrict__ ei, const float* __restrict__ ef,
        const int* __restrict__ ofs, const uchar2* __restrict__ rank,
        unsigned* __restrict__ em_val, int* __restrict__ ec_val) {
    int e = blockIdx.x * 256 + threadIdx.x;
    if (e >= NE) return;
    int src = ei[e];
    int dst = ei[NE + e];
    int o = e / PER;
    uchar2 r = rank[e];
    int p1 = ofs[o * NN + src] + r.x;
    unsigned short eb = __half_as_ushort(__float2half_rn(ef[e]));
    em_val[p1] = ((unsigned)dst << 16) | (unsigned)eb;
    int p2 = ofs[4 * NN + dst] + r.y - NE;
    ec_val[p2] = src;
}

// ---------------- linear: x = relu(x @ W + b), scalar fp32 ------------------
template<int K>
__global__ __launch_bounds__(256) void lin_kernel(
        const float* __restrict__ xin,
        const float* __restrict__ W, const float* __restrict__ bias,
        float* __restrict__ xout) {
    __shared__ float xs[64][K + 1];
    int t = threadIdx.x;
    int n0 = blockIdx.x * 64;
    for (int idx = t; idx < 64 * K; idx += 256) {
        int n = idx / K, k = idx - n * K;
        int g = n0 + n;
        xs[n][k] = (g < NN) ? xin[(size_t)g * K + k] : 0.f;
    }
    __syncthreads();
    int ng = t >> 4;
    int f0 = (t & 15) * 4;
    float acc[4][4] = {};
    for (int k = 0; k < K; ++k) {
        float4 w4 = *(const float4*)&W[k * HD + f0];
        #pragma unroll
        for (int j = 0; j < 4; ++j) {
            float xv = xs[ng * 4 + j][k];
            acc[j][0] += xv * w4.x; acc[j][1] += xv * w4.y;
            acc[j][2] += xv * w4.z; acc[j][3] += xv * w4.w;
        }
    }
    float4 b4 = *(const float4*)&bias[f0];
    #pragma unroll
    for (int j = 0; j < 4; ++j) {
        int g = n0 + ng * 4 + j;
        if (g < NN) {
            float4 o;
            o.x = fmaxf(acc[j][0] + b4.x, 0.f);
            o.y = fmaxf(acc[j][1] + b4.y, 0.f);
            o.z = fmaxf(acc[j][2] + b4.z, 0.f);
            o.w = fmaxf(acc[j][3] + b4.w, 0.f);
            *(float4*)&xout[(size_t)g * HD + f0] = o;
        }
    }
}

// ---------------- u/v via MFMA, split-fp16 (R5 version, known-good) --------
__global__ __launch_bounds__(256) void uv_mfma(
        const float* __restrict__ x,
        const _Float16* __restrict__ Wuh, const _Float16* __restrict__ Wul,
        const _Float16* __restrict__ Wvh, const _Float16* __restrict__ Wvl,
        const float* __restrict__ bias,
        _Float16* __restrict__ u, _Float16* __restrict__ v) {
    __shared__ _Float16 xh[64 * 72], xl[64 * 72];
    __shared__ _Float16 wuh[64 * 72], wul[64 * 72];
    __shared__ _Float16 wvh[64 * 72], wvl[64 * 72];
    __shared__ _Float16 rp[4 * 16 * 72];
    int t = threadIdx.x;
    int n0 = blockIdx.x * 64;

    { // stage x (split) : thread t -> node t>>2, 16 k at (t&3)*16
        int node = t >> 2, k0 = (t & 3) * 16;
        int g = n0 + node;
        float f[16];
        if (g < NN) {
            const float4* xr = (const float4*)&x[(size_t)g * HD + k0];
            *(float4*)&f[0] = xr[0]; *(float4*)&f[4] = xr[1];
            *(float4*)&f[8] = xr[2]; *(float4*)&f[12] = xr[3];
        } else {
            #pragma unroll
            for (int j = 0; j < 16; ++j) f[j] = 0.f;
        }
        half8 h0, h1, l0, l1;
        #pragma unroll
        for (int j = 0; j < 8; ++j) {
            _Float16 h = (_Float16)f[j];
            h0[j] = h; l0[j] = (_Float16)(f[j] - (float)h);
            _Float16 g2 = (_Float16)f[j + 8];
            h1[j] = g2; l1[j] = (_Float16)(f[j + 8] - (float)g2);
        }
        *(half8*)&xh[node * 72 + k0] = h0; *(half8*)&xh[node * 72 + k0 + 8] = h1;
        *(half8*)&xl[node * 72 + k0] = l0; *(half8*)&xl[node * 72 + k0 + 8] = l1;
    }
    { // stage W (4 arrays), row remap into 72-padded LDS
        int n = t >> 2, c = (t & 3) * 16;
        *(half8*)&wuh[n * 72 + c]     = *(const half8*)&Wuh[n * 64 + c];
        *(half8*)&wuh[n * 72 + c + 8] = *(const half8*)&Wuh[n * 64 + c + 8];
        *(half8*)&wul[n * 72 + c]     = *(const half8*)&Wul[n * 64 + c];
        *(half8*)&wul[n * 72 + c + 8] = *(const half8*)&Wul[n * 64 + c + 8];
        *(half8*)&wvh[n * 72 + c]     = *(const half8*)&Wvh[n * 64 + c];
        *(half8*)&wvh[n * 72 + c + 8] = *(const half8*)&Wvh[n * 64 + c + 8];
        *(half8*)&wvl[n * 72 + c]     = *(const half8*)&Wvl[n * 64 + c];
        *(half8*)&wvl[n * 72 + c + 8] = *(const half8*)&Wvl[n * 64 + c + 8];
    }
    __syncthreads();

    int w = t >> 6, lane = t & 63;
    int quad = lane >> 4, l16 = lane & 15;
    int m0 = w * 16;
    half8 ah0 = *(half8*)&xh[(m0 + l16) * 72 + quad * 8];
    half8 ah1 = *(half8*)&xh[(m0 + l16) * 72 + 32 + quad * 8];
    half8 al0 = *(half8*)&xl[(m0 + l16) * 72 + quad * 8];
    half8 al1 = *(half8*)&xl[(m0 + l16) * 72 + 32 + quad * 8];

    float4v au[4], av[4];
    #pragma unroll
    for (int nt = 0; nt < 4; ++nt) {
        int n = nt * 16 + l16;
        half8 bh0 = *(half8*)&wuh[n * 72 + quad * 8];
        half8 bh1 = *(half8*)&wuh[n * 72 + 32 + quad * 8];
        half8 bl0 = *(half8*)&wul[n * 72 + quad * 8];
        half8 bl1 = *(half8*)&wul[n * 72 + 32 + quad * 8];
        float4v acc = {0.f, 0.f, 0.f, 0.f};
        acc = __builtin_amdgcn_mfma_f32_16x16x32_f16(ah0, bh0, acc, 0, 0, 0);
        acc = __builtin_amdgcn_mfma_f32_16x16x32_f16(ah1, bh1, acc, 0, 0, 0);
        acc = __builtin_amdgcn_mfma_f32_16x16x32_f16(al0, bh0, acc, 0, 0, 0);
        acc = __builtin_amdgcn_mfma_f32_16x16x32_f16(al1, bh1, acc, 0, 0, 0);
        acc = __builtin_amdgcn_mfma_f32_16x16x32_f16(ah0, bl0, acc, 0, 0, 0);
        acc = __builtin_amdgcn_mfma_f32_16x16x32_f16(ah1, bl1, acc, 0, 0, 0);
        au[nt] = acc;
        half8 ch0 = *(half8*)&wvh[n * 72 + quad * 8];
        half8 ch1 = *(half8*)&wvh[n * 72 + 32 + quad * 8];
        half8 cl0 = *(half8*)&wvl[n * 72 + quad * 8];
        half8 cl1 = *(half8*)&wvl[n * 72 + 32 + quad * 8];
        float4v accv = {0.f, 0.f, 0.f, 0.f};
        accv = __builtin_amdgcn_mfma_f32_16x16x32_f16(ah0, ch0, accv, 0, 0, 0);
        accv = __builtin_amdgcn_mfma_f32_16x16x32_f16(ah1, ch1, accv, 0, 0, 0);
        accv = __builtin_amdgcn_mfma_f32_16x16x32_f16(al0, ch0, accv, 0, 0, 0);
        accv = __builtin_amdgcn_mfma_f32_16x16x32_f16(al1, ch1, accv, 0, 0, 0);
        accv = __builtin_amdgcn_mfma_f32_16x16x32_f16(ah0, cl0, accv, 0, 0, 0);
        accv = __builtin_amdgcn_mfma_f32_16x16x32_f16(ah1, cl1, accv, 0, 0, 0);
        av[nt] = accv;
    }

    // repack u (+bias) through per-wave LDS, store 16B vectors
    _Float16* rpw = &rp[w * 16 * 72];
    #pragma unroll
    for (int nt = 0; nt < 4; ++nt) {
        float bn = bias[nt * 16 + l16];
        #pragma unroll
        for (int r = 0; r < 4; ++r)
            rpw[(quad * 4 + r) * 72 + nt * 16 + l16] = (_Float16)(au[nt][r] + bn);
    }
    int mr = lane >> 2, cr = (lane & 3) * 16;
    int gr = n0 + m0 + mr;
    if (gr < NN) {
        *(half8*)&u[(size_t)gr * HD + cr]     = *(half8*)&rpw[mr * 72 + cr];
        *(half8*)&u[(size_t)gr * HD + cr + 8] = *(half8*)&rpw[mr * 72 + cr + 8];
    }
    #pragma unroll
    for (int nt = 0; nt < 4; ++nt) {
        #pragma unroll
        for (int r = 0; r < 4; ++r)
            rpw[(quad * 4 + r) * 72 + nt * 16 + l16] = (_Float16)(av[nt][r]);
    }
    if (gr < NN) {
        *(half8*)&v[(size_t)gr * HD + cr]     = *(half8*)&rpw[mr * 72 + cr];
        *(half8*)&v[(size_t)gr * HD + cr + 8] = *(half8*)&rpw[mr * 72 + cr + 8];
    }
}

// load 8 consecutive halves (16B aligned) -> 8 floats
__device__ __forceinline__ void load_h8(const __half* p, float* o) {
    float4 r = *(const float4*)p;
    __half2 h0 = *reinterpret_cast<__half2*>(&r.x);
    __half2 h1 = *reinterpret_cast<__half2*>(&r.y);
    __half2 h2 = *reinterpret_cast<__half2*>(&r.z);
    __half2 h3 = *reinterpret_cast<__half2*>(&r.w);
    float2 f0 = __half22float2(h0), f1 = __half22float2(h1);
    float2 f2 = __half22float2(h2), f3 = __half22float2(h3);
    o[0] = f0.x; o[1] = f0.y; o[2] = f1.x; o[3] = f1.y;
    o[4] = f2.x; o[5] = f2.y; o[6] = f3.x; o[7] = f3.y;
}

// ---------------- emulsion edge pass + fold --------------------------------
// 8 nodes/wave, 8 lanes/node, 8 features/lane.
// x[n] = (x[n] + sum_e relu(u[dst]+v[n]+ef*we)) / 2   (node-local update)
__global__ __launch_bounds__(256) void em_edge(
        const unsigned* __restrict__ em_val, const int* __restrict__ ofs,
        const __half* __restrict__ u, const __half* __restrict__ v,
        const float* __restrict__ we, float* __restrict__ x, int order) {
    int t = threadIdx.x;
    int node = blockIdx.x * 32 + (t >> 3);
    if (node >= NN) return;
    int f0 = (t & 7) * 8;
    int key = order * NN + node;
    int s0 = ofs[key], s1 = ofs[key + 1];
    float vn[8], wef[8], acc[8] = {};
    load_h8(&v[(size_t)node * HD + f0], vn);
    *(float4*)&wef[0] = *(const float4*)&we[f0];
    *(float4*)&wef[4] = *(const float4*)&we[f0 + 4];
    int p = s0;
    for (; p + 2 <= s1; p += 2) {
        unsigned e0 = em_val[p], e1 = em_val[p + 1];
        float u0[8], u1[8];
        load_h8(&u[(size_t)(e0 >> 16) * HD + f0], u0);
        load_h8(&u[(size_t)(e1 >> 16) * HD + f0], u1);
        float ef0 = __half2float(__ushort_as_half((unsigned short)(e0 & 0xffff)));
        float ef1 = __half2float(__ushort_as_half((unsigned short)(e1 & 0xffff)));
        #pragma unroll
        for (int j = 0; j < 8; ++j) {
            acc[j] += fmaxf(u0[j] + vn[j] + ef0 * wef[j], 0.f)
                    + fmaxf(u1[j] + vn[j] + ef1 * wef[j], 0.f);
        }
    }
    if (p < s1) {
        unsigned e0 = em_val[p];
        float u0[8];
        load_h8(&u[(size_t)(e0 >> 16) * HD + f0], u0);
        float ef0 = __half2float(__ushort_as_half((unsigned short)(e0 & 0xffff)));
        #pragma unroll
        for (int j = 0; j < 8; ++j)
            acc[j] += fmaxf(u0[j] + vn[j] + ef0 * wef[j], 0.f);
    }
    float xr[8];
    *(float4*)&xr[0] = *(const float4*)&x[(size_t)node * HD + f0];
    *(float4*)&xr[4] = *(const float4*)&x[(size_t)node * HD + f0 + 4];
    #pragma unroll
    for (int j = 0; j < 8; ++j) xr[j] = (xr[j] + acc[j]) * 0.5f;
    *(float4*)&x[(size_t)node * HD + f0] = *(float4*)&xr[0];
    *(float4*)&x[(size_t)node * HD + f0 + 4] = *(float4*)&xr[4];
}

// ---------------- edge conv pass: x[n] = max(0, max_e (u[n]+v[src])) -------
__global__ __launch_bounds__(256) void ec_edge(
        const int* __restrict__ ec_val, const int* __restrict__ ofs,
        const __half* __restrict__ u, const __half* __restrict__ v,
        float* __restrict__ x) {
    int t = threadIdx.x;
    int node = blockIdx.x * 32 + (t >> 3);
    if (node >= NN) return;
    int f0 = (t & 7) * 8;
    int s0 = ofs[4 * NN + node] - NE, s1 = ofs[4 * NN + node + 1] - NE;
    float un[8], m[8] = {};  // init 0: empty -> 0, and relu'd msgs >= 0
    load_h8(&u[(size_t)node * HD + f0], un);
    int p = s0;
    for (; p + 2 <= s1; p += 2) {
        int i0 = ec_val[p], i1 = ec_val[p + 1];
        float v0[8], v1[8];
        load_h8(&v[(size_t)i0 * HD + f0], v0);
        load_h8(&v[(size_t)i1 * HD + f0], v1);
        #pragma unroll
        for (int j = 0; j < 8; ++j)
            m[j] = fmaxf(m[j], fmaxf(un[j] + v0[j], un[j] + v1[j]));
    }
    if (p < s1) {
        int i0 = ec_val[p];
        float v0[8];
        load_h8(&v[(size_t)i0 * HD + f0], v0);
        #pragma unroll
        for (int j = 0; j < 8; ++j) m[j] = fmaxf(m[j], un[j] + v0[j]);
    }
    *(float4*)&x[(size_t)node * HD + f0] = *(float4*)&m[0];
    *(float4*)&x[(size_t)node * HD + f0 + 4] = *(float4*)&m[4];
}

// ---------------- last ec pass fused with output projection ----------------
// computes m[8] like ec_edge, routes through LDS, applies out = m @ ow + ob.
__global__ __launch_bounds__(256) void ec_out(
        const int* __restrict__ ec_val, const int* __restrict__ ofs,
        const __half* __restrict__ u, const __half* __restrict__ v,
        const float* __restrict__ ow, const float* __restrict__ ob,
        float* __restrict__ out) {
    __shared__ float xs[32][72];
    int t = threadIdx.x;
    int nl = t >> 3;                     // local node 0..31
    int node = blockIdx.x * 32 + nl;
    int f0 = (t & 7) * 8;
    float m[8] = {};
    if (node < NN) {
        int s0 = ofs[4 * NN + node] - NE, s1 = ofs[4 * NN + node + 1] - NE;
        float un[8];
        load_h8(&u[(size_t)node * HD + f0], un);
        int p = s0;
        for (; p + 2 <= s1; p += 2) {
            int i0 = ec_val[p], i1 = ec_val[p + 1];
            float v0[8], v1[8];
            load_h8(&v[(size_t)i0 * HD + f0], v0);
            load_h8(&v[(size_t)i1 * HD + f0], v1);
            #pragma unroll
            for (int j = 0; j < 8; ++j)
                m[j] = fmaxf(m[j], fmaxf(un[j] + v0[j], un[j] + v1[j]));
        }
        if (p < s1) {
            int i0 = ec_val[p];
            float v0[8];
            load_h8(&v[(size_t)i0 * HD + f0], v0);
            #pragma unroll
            for (int j = 0; j < 8; ++j) m[j] = fmaxf(m[j], un[j] + v0[j]);
        }
    }
    #pragma unroll
    for (int j = 0; j < 8; ++j) xs[nl][f0 + j] = m[j];
    __syncthreads();
    for (int idx = t; idx < 32 * 10; idx += 256) {
        int n = idx / 10, f = idx - n * 10;
        int g = blockIdx.x * 32 + n;
        if (g >= NN) continue;
        float acc = ob[f];
        #pragma unroll
        for (int k = 0; k < HD; ++k) acc += xs[n][k] * ow[k * 10 + f];
        out[(size_t)g * 10 + f] = acc;
    }
}

extern "C" void kernel_launch(void* const* d_in, const int* in_sizes, int n_in,
                              void* d_out, int out_size, void* d_ws, size_t ws_size,
                              hipStream_t stream) {
    const float* x_in  = (const float*)d_in[0];
    const int*   ei    = (const int*)d_in[1];
    const float* ef    = (const float*)d_in[2];
    const float* lw[3] = {(const float*)d_in[3], (const float*)d_in[5], (const float*)d_in[7]};
    const float* lb[3] = {(const float*)d_in[4], (const float*)d_in[6], (const float*)d_in[8]};
    const float* em_w  = (const float*)d_in[9];
    const float* em_b  = (const float*)d_in[10];
    const float* ec_w  = (const float*)d_in[11];
    const float* ec_b  = (const float*)d_in[12];
    const float* ow    = (const float*)d_in[13];
    const float* ob    = (const float*)d_in[14];
    float* out = (float*)d_out;

    char* wsb = (char*)d_ws;
    size_t off = 0;
    auto alloc = [&](size_t bytes) {
        void* p = wsb + off;
        off = (off + bytes + 255) & ~(size_t)255;
        return p;
    };
    float*     x      = (float*)alloc((size_t)NN * HD * 4);
    _Float16*  u      = (_Float16*)alloc((size_t)NN * HD * 2);
    _Float16*  v      = (_Float16*)alloc((size_t)NN * HD * 2);
    int*       cnt    = (int*)alloc((size_t)NKEY * 4);
    int*       ofs    = (int*)alloc((size_t)NKEY * 4);
    int*       bsum   = (int*)alloc((size_t)1024 * 4);
    int*       bofs   = (int*)alloc((size_t)1024 * 4);
    uchar2*    rank   = (uchar2*)alloc((size_t)NE * 2);
    unsigned*  em_val = (unsigned*)alloc((size_t)NE * 4);
    int*       ec_val = (int*)alloc((size_t)NE * 4);
    _Float16*  wh     = (_Float16*)alloc((size_t)24 * 4096 * 2);
    (void)ws_size; (void)in_sizes; (void)n_in; (void)out_size;

    const int gb_nodes = (NN + 63) / 64;   // 782
    const int gb_edges = (NE + 255) / 256; // 3125
    const int gb_n8    = (NN + 31) / 32;   // 1563
    const int gb_keys  = NKEY / 256;       // 977

    // ---- setup: count + lin0 + prep_w fused; then scan + fill ----
    hipMemsetAsync(cnt, 0, (size_t)NKEY * 4, stream);
    setup_kernel<<<NB_COUNT + NB_LIN + NB_PREP, 256, 0, stream>>>(
        ei, cnt, rank, x_in, lw[0], lb[0], x, em_w, ec_w, wh);
    scan_blk<<<gb_keys, 256, 0, stream>>>(cnt, bsum);
    scan_top<<<1, 1024, 0, stream>>>(bsum, bofs, gb_keys);
    scan_fin<<<gb_keys, 256, 0, stream>>>(cnt, bofs, ofs);
    fill_kernel<<<gb_edges, 256, 0, stream>>>(ei, ef, ofs, rank, em_val, ec_val);

    // ---- network ----
    for (int i = 0; i < 3; ++i) {
        const _Float16* Wuh = wh + (size_t)i * 4096;
        const _Float16* Wvh = wh + (size_t)(3 + i) * 4096;
        const _Float16* Wul = wh + (size_t)(12 + i) * 4096;
        const _Float16* Wvl = wh + (size_t)(15 + i) * 4096;
        const float* bi = em_b + (size_t)i * HD;
        const float* we = em_w + (size_t)i * 129 * HD + 128 * HD;
        for (int o = 0; o < 4; ++o) {
            uv_mfma<<<gb_nodes, 256, 0, stream>>>(x, Wuh, Wul, Wvh, Wvl, bi, u, v);
            em_edge<<<gb_n8, 256, 0, stream>>>(em_val, ofs, (const __half*)u,
                                               (const __half*)v, we, x, o);
        }
        if (i < 2)
            lin_kernel<64><<<gb_nodes, 256, 0, stream>>>(x, lw[i + 1], lb[i + 1], x);
    }

    for (int j = 0; j < 3; ++j) {
        const _Float16* Wuh = wh + (size_t)(6 + j) * 4096;
        const _Float16* Wvh = wh + (size_t)(9 + j) * 4096;
        const _Float16* Wul = wh + (size_t)(18 + j) * 4096;
        const _Float16* Wvl = wh + (size_t)(21 + j) * 4096;
        const float* bj = ec_b + (size_t)j * HD;
        uv_mfma<<<gb_nodes, 256, 0, stream>>>(x, Wuh, Wul, Wvh, Wvl, bj, u, v);
        if (j < 2)
            ec_edge<<<gb_n8, 256, 0, stream>>>(ec_val, ofs, (const __half*)u,
                                               (const __half*)v, x);
        else
            ec_out<<<gb_n8, 256, 0, stream>>>(ec_val, ofs, (const __half*)u,
                                              (const __half*)v, ow, ob, out);
    }
}